// Round 1
// baseline (17848.691 us; speedup 1.0000x reference)
//
#include <hip/hip_runtime.h>
#include <hip/hip_bf16.h>

#define T_SEQ 8192
#define E_DIM 256
#define H_DIM 512
#define G4    2048   // 4*H

// ======================================================================
// K1: pre[dir][t][0:2048] = emb[sent(dir,t)] @ W_ih[dir]^T + (b_ih+b_hh)
// dir==1 uses reversed time (sent[T-1-t]) so the scan kernel can run both
// directions forward over t.
// 64x64 output tile, K staged in 64-chunks, fp32.
// ======================================================================
__global__ __launch_bounds__(256, 4)
void k_pre(const int* __restrict__ sent, const float* __restrict__ emb,
           const float* __restrict__ Wf, const float* __restrict__ Wb,
           const float* __restrict__ bif, const float* __restrict__ bhf,
           const float* __restrict__ bib, const float* __restrict__ bhb,
           float* __restrict__ pre)
{
    const int jt  = blockIdx.x;      // gate-row tile (64 rows), 0..31
    const int tt  = blockIdx.y;      // time tile (64 rows), 0..127
    const int dir = blockIdx.z;
    const float* W  = dir ? Wb : Wf;
    const float* bi = dir ? bib : bif;
    const float* bh = dir ? bhb : bhf;
    float* pred = pre + (size_t)dir * T_SEQ * G4;

    __shared__ float xs[64][65];   // +1 pad: 2-way max bank alias (free)
    __shared__ float ws[64][65];
    __shared__ int   ss[64];

    const int tid = threadIdx.x;
    if (tid < 64) {
        int trow = tt * 64 + tid;
        ss[tid] = sent[dir ? (T_SEQ - 1 - trow) : trow];
    }

    const int ty = tid >> 4, tx = tid & 15;
    const int lrow  = tid >> 2;        // staging row 0..63
    const int cbase = (tid & 3) * 16;  // staging col base

    float acc[4][4] = {{0.f}};

    for (int kk0 = 0; kk0 < E_DIM; kk0 += 64) {
        __syncthreads();
        #pragma unroll
        for (int c = 0; c < 4; ++c) {
            int col = cbase + c * 4;
            float4 xv = *reinterpret_cast<const float4*>(emb + (size_t)ss[lrow] * E_DIM + kk0 + col);
            float4 wv = *reinterpret_cast<const float4*>(W + (size_t)(jt * 64 + lrow) * E_DIM + kk0 + col);
            xs[lrow][col+0] = xv.x; xs[lrow][col+1] = xv.y; xs[lrow][col+2] = xv.z; xs[lrow][col+3] = xv.w;
            ws[lrow][col+0] = wv.x; ws[lrow][col+1] = wv.y; ws[lrow][col+2] = wv.z; ws[lrow][col+3] = wv.w;
        }
        __syncthreads();
        #pragma unroll 8
        for (int k = 0; k < 64; ++k) {
            float a0 = xs[ty*4+0][k], a1 = xs[ty*4+1][k], a2 = xs[ty*4+2][k], a3 = xs[ty*4+3][k];
            float b0 = ws[tx*4+0][k], b1 = ws[tx*4+1][k], b2 = ws[tx*4+2][k], b3 = ws[tx*4+3][k];
            acc[0][0] = fmaf(a0,b0,acc[0][0]); acc[0][1] = fmaf(a0,b1,acc[0][1]);
            acc[0][2] = fmaf(a0,b2,acc[0][2]); acc[0][3] = fmaf(a0,b3,acc[0][3]);
            acc[1][0] = fmaf(a1,b0,acc[1][0]); acc[1][1] = fmaf(a1,b1,acc[1][1]);
            acc[1][2] = fmaf(a1,b2,acc[1][2]); acc[1][3] = fmaf(a1,b3,acc[1][3]);
            acc[2][0] = fmaf(a2,b0,acc[2][0]); acc[2][1] = fmaf(a2,b1,acc[2][1]);
            acc[2][2] = fmaf(a2,b2,acc[2][2]); acc[2][3] = fmaf(a2,b3,acc[2][3]);
            acc[3][0] = fmaf(a3,b0,acc[3][0]); acc[3][1] = fmaf(a3,b1,acc[3][1]);
            acc[3][2] = fmaf(a3,b2,acc[3][2]); acc[3][3] = fmaf(a3,b3,acc[3][3]);
        }
    }

    const int colg = jt * 64 + tx * 4;
    float bs[4];
    #pragma unroll
    for (int j = 0; j < 4; ++j) bs[j] = bi[colg + j] + bh[colg + j];
    #pragma unroll
    for (int i = 0; i < 4; ++i) {
        float4 r;
        r.x = acc[i][0] + bs[0]; r.y = acc[i][1] + bs[1];
        r.z = acc[i][2] + bs[2]; r.w = acc[i][3] + bs[3];
        *reinterpret_cast<float4*>(pred + (size_t)(tt*64 + ty*4 + i) * G4 + colg) = r;
    }
}

// ======================================================================
// K2: the two LSTM scans. 32 persistent blocks (16/dir), 1024 thr each.
// Block b owns h-elements [b*32, b*32+32) -> 128 gate rows; its 256 KB
// W_hh slice lives in registers (64 f32/thread).
// Per step: all 512 h values are exchanged through step-tagged 64-bit
// agent-scope atomic slots (tag=stored step; parity double-buffer).
// Lane map (per wave, 2 h-elems): j_idx=lane>>5, gate=(lane>>3)&3,
// seg=lane&7 (64 cols). Reduce over the 8 seg lanes via shfl_xor.
// ======================================================================
__global__ __launch_bounds__(1024, 1)
void k_scan(const float* __restrict__ pre,
            const float* __restrict__ Whhf, const float* __restrict__ Whhb,
            const float* __restrict__ h0, const float* __restrict__ c0,
            float* __restrict__ hcat, unsigned long long* __restrict__ hbuf)
{
    const int dir  = blockIdx.x >> 4;
    const int b    = blockIdx.x & 15;
    const int tid  = threadIdx.x;
    const int wv   = tid >> 6;
    const int lane = tid & 63;
    const int j_idx = lane >> 5;
    const int g     = (lane >> 3) & 3;
    const int s     = lane & 7;
    const int j_global = b * 32 + 2 * wv + j_idx;
    const int row      = g * H_DIM + j_global;      // PyTorch gate order i,f,g,o

    // load W_hh slice into registers: 64 consecutive cols of one row
    const float* Whh  = dir ? Whhb : Whhf;
    const float* wrow = Whh + (size_t)row * H_DIM + s * 64;
    float w[64];
    #pragma unroll
    for (int k = 0; k < 64; k += 4) {
        float4 v = *reinterpret_cast<const float4*>(wrow + k);
        w[k] = v.x; w[k+1] = v.y; w[k+2] = v.z; w[k+3] = v.w;
    }

    unsigned long long* hb = hbuf + dir * 1024;     // [parity][512]
    const float* pred = pre + (size_t)dir * T_SEQ * G4;

    // h staging in LDS, segment-padded (stride 68 words) => conflict-free
    __shared__ float hsh[2][8 * 68];

    // publish initial h0 for own slice (tag 0, parity 0)
    if (tid < 32) {
        int j = b * 32 + tid;
        unsigned long long pv = (unsigned long long)__float_as_uint(h0[dir * H_DIM + j]);
        __hip_atomic_store(&hb[j], pv, __ATOMIC_RELAXED, __HIP_MEMORY_SCOPE_AGENT);
    }
    __threadfence();   // order init stores before any later tagged store
    __syncthreads();

    const bool coll = ((lane & 31) == 0);           // gate collector lanes
    float c_reg = coll ? c0[dir * H_DIM + j_global] : 0.f;
    float pre_row = (s == 0) ? pred[row] : 0.f;     // prefetch t=0

    for (int t = 0; t < T_SEQ; ++t) {
        const int par = t & 1;
        if (tid < 512) {
            unsigned long long v;
            do {
                v = __hip_atomic_load(&hb[par * 512 + tid], __ATOMIC_RELAXED, __HIP_MEMORY_SCOPE_AGENT);
            } while ((unsigned)(v >> 32) != (unsigned)t);
            hsh[par][(tid >> 6) * 68 + (tid & 63)] = __uint_as_float((unsigned)v);
        }
        __syncthreads();

        // matvec: this lane covers 1 row x 64 cols
        const float* hv = &hsh[par][s * 68];
        float a0 = 0.f, a1 = 0.f, a2 = 0.f, a3 = 0.f;
        #pragma unroll
        for (int k = 0; k < 64; k += 16) {
            float4 p0 = *reinterpret_cast<const float4*>(hv + k);
            float4 p1 = *reinterpret_cast<const float4*>(hv + k + 4);
            float4 p2 = *reinterpret_cast<const float4*>(hv + k + 8);
            float4 p3 = *reinterpret_cast<const float4*>(hv + k + 12);
            a0 = fmaf(p0.x, w[k+0], a0);  a0 = fmaf(p0.y, w[k+1], a0);
            a0 = fmaf(p0.z, w[k+2], a0);  a0 = fmaf(p0.w, w[k+3], a0);
            a1 = fmaf(p1.x, w[k+4], a1);  a1 = fmaf(p1.y, w[k+5], a1);
            a1 = fmaf(p1.z, w[k+6], a1);  a1 = fmaf(p1.w, w[k+7], a1);
            a2 = fmaf(p2.x, w[k+8], a2);  a2 = fmaf(p2.y, w[k+9], a2);
            a2 = fmaf(p2.z, w[k+10], a2); a2 = fmaf(p2.w, w[k+11], a2);
            a3 = fmaf(p3.x, w[k+12], a3); a3 = fmaf(p3.y, w[k+13], a3);
            a3 = fmaf(p3.z, w[k+14], a3); a3 = fmaf(p3.w, w[k+15], a3);
        }
        float acc = (a0 + a1) + (a2 + a3);
        acc += __shfl_xor(acc, 1);
        acc += __shfl_xor(acc, 2);
        acc += __shfl_xor(acc, 4);
        float gatev = acc + pre_row;                 // valid on s==0 lanes

        if (s == 0 && t + 1 < T_SEQ)                 // prefetch next pre
            pre_row = pred[(size_t)(t + 1) * G4 + row];

        const int base = lane & 32;
        float gi = __shfl(gatev, base + 0);
        float gf = __shfl(gatev, base + 8);
        float gc = __shfl(gatev, base + 16);
        float go = __shfl(gatev, base + 24);
        if (coll) {
            float ig = 1.f / (1.f + __expf(-gi));
            float fg = 1.f / (1.f + __expf(-gf));
            float cc = tanhf(gc);
            float og = 1.f / (1.f + __expf(-go));
            c_reg = fg * c_reg + ig * cc;
            float h = og * tanhf(c_reg);
            unsigned long long pv = ((unsigned long long)(unsigned)(t + 1) << 32)
                                  | (unsigned long long)__float_as_uint(h);
            __hip_atomic_store(&hb[((t + 1) & 1) * 512 + j_global], pv,
                               __ATOMIC_RELAXED, __HIP_MEMORY_SCOPE_AGENT);
            int ta = dir ? (T_SEQ - 1 - t) : t;
            hcat[(size_t)ta * 1024 + dir * H_DIM + j_global] = h;
        }
        // no second barrier needed: hsh is parity double-buffered and the
        // next iteration's barrier orders reads-before-overwrite.
    }
}

// ======================================================================
// K3: out[t][k] = hcat[t] . W_out[k] + b_out[k]. One wave per t-row;
// lane owns 16 cols, butterfly-reduce per k.
// ======================================================================
__global__ __launch_bounds__(256, 4)
void k_out(const float* __restrict__ hcat, const float* __restrict__ Wout,
           const float* __restrict__ bout, float* __restrict__ out)
{
    const int lane = threadIdx.x & 63;
    const int gw   = (blockIdx.x * 256 + threadIdx.x) >> 6;   // 0..1023
    for (int t = gw; t < T_SEQ; t += 1024) {
        const float* hr = hcat + (size_t)t * 1024 + lane * 16;
        float4 h4[4];
        #pragma unroll
        for (int i = 0; i < 4; ++i) h4[i] = *reinterpret_cast<const float4*>(hr + 4 * i);
        float res = 0.f;
        for (int k = 0; k < 32; ++k) {
            const float* wr = Wout + (size_t)k * 1024 + lane * 16;
            float p = 0.f;
            #pragma unroll
            for (int i = 0; i < 4; ++i) {
                float4 w4 = *reinterpret_cast<const float4*>(wr + 4 * i);
                p = fmaf(h4[i].x, w4.x, p); p = fmaf(h4[i].y, w4.y, p);
                p = fmaf(h4[i].z, w4.z, p); p = fmaf(h4[i].w, w4.w, p);
            }
            p += __shfl_xor(p, 1);  p += __shfl_xor(p, 2);  p += __shfl_xor(p, 4);
            p += __shfl_xor(p, 8);  p += __shfl_xor(p, 16); p += __shfl_xor(p, 32);
            if (lane == k) res = p;
        }
        if (lane < 32) out[(size_t)t * 32 + lane] = res + bout[lane];
    }
}

// ======================================================================
extern "C" void kernel_launch(void* const* d_in, const int* in_sizes, int n_in,
                              void* d_out, int out_size, void* d_ws, size_t ws_size,
                              hipStream_t stream) {
    const int*   sent = (const int*)  d_in[0];
    const float* emb  = (const float*)d_in[1];
    const float* Wihf = (const float*)d_in[2];
    const float* Whhf = (const float*)d_in[3];
    const float* bihf = (const float*)d_in[4];
    const float* bhhf = (const float*)d_in[5];
    const float* Wihb = (const float*)d_in[6];
    const float* Whhb = (const float*)d_in[7];
    const float* bihb = (const float*)d_in[8];
    const float* bhhb = (const float*)d_in[9];
    const float* Wout = (const float*)d_in[10];
    const float* bout = (const float*)d_in[11];
    const float* h0   = (const float*)d_in[12];
    const float* c0   = (const float*)d_in[13];
    float* out = (float*)d_out;

    // workspace layout: pre (128 MB) | hcat (32 MB) | hbuf (16 KB)
    float* pre  = (float*)d_ws;
    float* hcat = pre + (size_t)2 * T_SEQ * G4;
    unsigned long long* hbuf = (unsigned long long*)(hcat + (size_t)T_SEQ * 1024);

    dim3 g1(G4 / 64, T_SEQ / 64, 2);
    k_pre<<<g1, 256, 0, stream>>>(sent, emb, Wihf, Wihb, bihf, bhhf, bihb, bhhb, pre);
    k_scan<<<32, 1024, 0, stream>>>(pre, Whhf, Whhb, h0, c0, hcat, hbuf);
    k_out<<<256, 256, 0, stream>>>(hcat, Wout, bout, out);
}

// Round 2
// 14445.329 us; speedup vs baseline: 1.2356x; 1.2356x over previous
//
#include <hip/hip_runtime.h>
#include <hip/hip_bf16.h>

#define T_SEQ 8192
#define E_DIM 256
#define H_DIM 512
#define G4    2048   // 4*H

// ======================================================================
// K1: pre[dir][t][0:2048] = emb[sent(dir,t)] @ W_ih[dir]^T + (b_ih+b_hh)
// dir==1 uses reversed time (sent[T-1-t]) so the scan kernel can run both
// directions forward over t.
// ======================================================================
__global__ __launch_bounds__(256, 4)
void k_pre(const int* __restrict__ sent, const float* __restrict__ emb,
           const float* __restrict__ Wf, const float* __restrict__ Wb,
           const float* __restrict__ bif, const float* __restrict__ bhf,
           const float* __restrict__ bib, const float* __restrict__ bhb,
           float* __restrict__ pre)
{
    const int jt  = blockIdx.x;      // gate-row tile (64 rows), 0..31
    const int tt  = blockIdx.y;      // time tile (64 rows), 0..127
    const int dir = blockIdx.z;
    const float* W  = dir ? Wb : Wf;
    const float* bi = dir ? bib : bif;
    const float* bh = dir ? bhb : bhf;
    float* pred = pre + (size_t)dir * T_SEQ * G4;

    __shared__ float xs[64][65];
    __shared__ float ws[64][65];
    __shared__ int   ss[64];

    const int tid = threadIdx.x;
    if (tid < 64) {
        int trow = tt * 64 + tid;
        ss[tid] = sent[dir ? (T_SEQ - 1 - trow) : trow];
    }

    const int ty = tid >> 4, tx = tid & 15;
    const int lrow  = tid >> 2;
    const int cbase = (tid & 3) * 16;

    float acc[4][4] = {{0.f}};

    for (int kk0 = 0; kk0 < E_DIM; kk0 += 64) {
        __syncthreads();
        #pragma unroll
        for (int c = 0; c < 4; ++c) {
            int col = cbase + c * 4;
            float4 xv = *reinterpret_cast<const float4*>(emb + (size_t)ss[lrow] * E_DIM + kk0 + col);
            float4 wv = *reinterpret_cast<const float4*>(W + (size_t)(jt * 64 + lrow) * E_DIM + kk0 + col);
            xs[lrow][col+0] = xv.x; xs[lrow][col+1] = xv.y; xs[lrow][col+2] = xv.z; xs[lrow][col+3] = xv.w;
            ws[lrow][col+0] = wv.x; ws[lrow][col+1] = wv.y; ws[lrow][col+2] = wv.z; ws[lrow][col+3] = wv.w;
        }
        __syncthreads();
        #pragma unroll 8
        for (int k = 0; k < 64; ++k) {
            float a0 = xs[ty*4+0][k], a1 = xs[ty*4+1][k], a2 = xs[ty*4+2][k], a3 = xs[ty*4+3][k];
            float b0 = ws[tx*4+0][k], b1 = ws[tx*4+1][k], b2 = ws[tx*4+2][k], b3 = ws[tx*4+3][k];
            acc[0][0] = fmaf(a0,b0,acc[0][0]); acc[0][1] = fmaf(a0,b1,acc[0][1]);
            acc[0][2] = fmaf(a0,b2,acc[0][2]); acc[0][3] = fmaf(a0,b3,acc[0][3]);
            acc[1][0] = fmaf(a1,b0,acc[1][0]); acc[1][1] = fmaf(a1,b1,acc[1][1]);
            acc[1][2] = fmaf(a1,b2,acc[1][2]); acc[1][3] = fmaf(a1,b3,acc[1][3]);
            acc[2][0] = fmaf(a2,b0,acc[2][0]); acc[2][1] = fmaf(a2,b1,acc[2][1]);
            acc[2][2] = fmaf(a2,b2,acc[2][2]); acc[2][3] = fmaf(a2,b3,acc[2][3]);
            acc[3][0] = fmaf(a3,b0,acc[3][0]); acc[3][1] = fmaf(a3,b1,acc[3][1]);
            acc[3][2] = fmaf(a3,b2,acc[3][2]); acc[3][3] = fmaf(a3,b3,acc[3][3]);
        }
    }

    const int colg = jt * 64 + tx * 4;
    float bs[4];
    #pragma unroll
    for (int j = 0; j < 4; ++j) bs[j] = bi[colg + j] + bh[colg + j];
    #pragma unroll
    for (int i = 0; i < 4; ++i) {
        float4 r;
        r.x = acc[i][0] + bs[0]; r.y = acc[i][1] + bs[1];
        r.z = acc[i][2] + bs[2]; r.w = acc[i][3] + bs[3];
        *reinterpret_cast<float4*>(pred + (size_t)(tt*64 + ty*4 + i) * G4 + colg) = r;
    }
}

// ======================================================================
// K2: two LSTM scans, 32 persistent blocks (16/dir), 1024 thr each.
// W_hh slice register-resident (64 f32/thread, asm-pinned so the compiler
// cannot sink the loads back into the t-loop — Round1: VGPR=52 proved it
// re-fetched 256KB/block/step from L2 = the 4700cy/step bottleneck).
// h exchange: step-tagged 64-bit agent-scope atomic slots, parity dbuf.
// ======================================================================
__global__ __launch_bounds__(1024, 4)
void k_scan(const float* __restrict__ pre,
            const float* __restrict__ Whhf, const float* __restrict__ Whhb,
            const float* __restrict__ h0, const float* __restrict__ c0,
            float* __restrict__ hcat, unsigned long long* __restrict__ hbuf)
{
    const int dir  = blockIdx.x >> 4;
    const int b    = blockIdx.x & 15;
    const int tid  = threadIdx.x;
    const int wv   = tid >> 6;
    const int lane = tid & 63;
    const int j_idx = lane >> 5;
    const int g     = (lane >> 3) & 3;
    const int s     = lane & 7;
    const int j_global = b * 32 + 2 * wv + j_idx;
    const int row      = g * H_DIM + j_global;      // PyTorch gate order i,f,g,o

    // W_hh slice into registers: 64 consecutive cols of one row
    const float* Whh  = dir ? Whhb : Whhf;
    const float* wrow = Whh + (size_t)row * H_DIM + s * 64;
    float w[64];
    #pragma unroll
    for (int k = 0; k < 64; k += 4) {
        float4 v = *reinterpret_cast<const float4*>(wrow + k);
        w[k] = v.x; w[k+1] = v.y; w[k+2] = v.z; w[k+3] = v.w;
    }
    // pin: values become opaque -> cannot be rematerialized from memory
    #pragma unroll
    for (int k = 0; k < 64; ++k) asm volatile("" : "+v"(w[k]));

    unsigned long long* hb = hbuf + dir * 1024;     // [parity][512]
    const float* pred = pre + (size_t)dir * T_SEQ * G4;

    __shared__ float hsh[2][8 * 68];   // segment-padded, conflict-free

    if (tid < 32) {
        int j = b * 32 + tid;
        unsigned long long pv = (unsigned long long)__float_as_uint(h0[dir * H_DIM + j]);
        __hip_atomic_store(&hb[j], pv, __ATOMIC_RELAXED, __HIP_MEMORY_SCOPE_AGENT);
    }
    __threadfence();
    __syncthreads();

    const bool coll = ((lane & 31) == 0);           // gate collector lanes
    float c_reg = coll ? c0[dir * H_DIM + j_global] : 0.f;
    float pre_row = (s == 0) ? pred[row] : 0.f;     // prefetch t=0

    for (int t = 0; t < T_SEQ; ++t) {
        const int par = t & 1;
        if (tid < 512) {
            unsigned long long v;
            do {
                v = __hip_atomic_load(&hb[par * 512 + tid], __ATOMIC_RELAXED, __HIP_MEMORY_SCOPE_AGENT);
            } while ((unsigned)(v >> 32) != (unsigned)t);
            hsh[par][(tid >> 6) * 68 + (tid & 63)] = __uint_as_float((unsigned)v);
        }
        __syncthreads();

        const float* hv = &hsh[par][s * 68];
        float a0 = 0.f, a1 = 0.f, a2 = 0.f, a3 = 0.f;
        #pragma unroll
        for (int k = 0; k < 64; k += 16) {
            float4 p0 = *reinterpret_cast<const float4*>(hv + k);
            float4 p1 = *reinterpret_cast<const float4*>(hv + k + 4);
            float4 p2 = *reinterpret_cast<const float4*>(hv + k + 8);
            float4 p3 = *reinterpret_cast<const float4*>(hv + k + 12);
            a0 = fmaf(p0.x, w[k+0], a0);  a0 = fmaf(p0.y, w[k+1], a0);
            a0 = fmaf(p0.z, w[k+2], a0);  a0 = fmaf(p0.w, w[k+3], a0);
            a1 = fmaf(p1.x, w[k+4], a1);  a1 = fmaf(p1.y, w[k+5], a1);
            a1 = fmaf(p1.z, w[k+6], a1);  a1 = fmaf(p1.w, w[k+7], a1);
            a2 = fmaf(p2.x, w[k+8], a2);  a2 = fmaf(p2.y, w[k+9], a2);
            a2 = fmaf(p2.z, w[k+10], a2); a2 = fmaf(p2.w, w[k+11], a2);
            a3 = fmaf(p3.x, w[k+12], a3); a3 = fmaf(p3.y, w[k+13], a3);
            a3 = fmaf(p3.z, w[k+14], a3); a3 = fmaf(p3.w, w[k+15], a3);
        }
        float acc = (a0 + a1) + (a2 + a3);
        acc += __shfl_xor(acc, 1);
        acc += __shfl_xor(acc, 2);
        acc += __shfl_xor(acc, 4);
        float gatev = acc + pre_row;                 // valid on s==0 lanes

        if (s == 0 && t + 1 < T_SEQ)                 // prefetch next pre
            pre_row = pred[(size_t)(t + 1) * G4 + row];

        // activation on the s==0 lane of each gate (parallel, not on the
        // collector's serial chain); g==2 is the tanh candidate gate
        float sg = 1.f / (1.f + __expf(-gatev));
        float th = tanhf(gatev);
        float act = (g == 2) ? th : sg;

        const int base = lane & 32;
        float ai = __shfl(act, base + 0);
        float af = __shfl(act, base + 8);
        float ac = __shfl(act, base + 16);
        float ao = __shfl(act, base + 24);
        if (coll) {
            c_reg = af * c_reg + ai * ac;
            float h = ao * tanhf(c_reg);
            unsigned long long pv = ((unsigned long long)(unsigned)(t + 1) << 32)
                                  | (unsigned long long)__float_as_uint(h);
            __hip_atomic_store(&hb[((t + 1) & 1) * 512 + j_global], pv,
                               __ATOMIC_RELAXED, __HIP_MEMORY_SCOPE_AGENT);
            int ta = dir ? (T_SEQ - 1 - t) : t;
            hcat[(size_t)ta * 1024 + dir * H_DIM + j_global] = h;
        }
        // hsh is parity double-buffered; next iteration's barrier orders
        // reads-before-overwrite.
    }
}

// ======================================================================
// K3: out[t][k] = hcat[t] . W_out[k] + b_out[k]
// ======================================================================
__global__ __launch_bounds__(256, 4)
void k_out(const float* __restrict__ hcat, const float* __restrict__ Wout,
           const float* __restrict__ bout, float* __restrict__ out)
{
    const int lane = threadIdx.x & 63;
    const int gw   = (blockIdx.x * 256 + threadIdx.x) >> 6;
    for (int t = gw; t < T_SEQ; t += 1024) {
        const float* hr = hcat + (size_t)t * 1024 + lane * 16;
        float4 h4[4];
        #pragma unroll
        for (int i = 0; i < 4; ++i) h4[i] = *reinterpret_cast<const float4*>(hr + 4 * i);
        float res = 0.f;
        for (int k = 0; k < 32; ++k) {
            const float* wr = Wout + (size_t)k * 1024 + lane * 16;
            float p = 0.f;
            #pragma unroll
            for (int i = 0; i < 4; ++i) {
                float4 w4 = *reinterpret_cast<const float4*>(wr + 4 * i);
                p = fmaf(h4[i].x, w4.x, p); p = fmaf(h4[i].y, w4.y, p);
                p = fmaf(h4[i].z, w4.z, p); p = fmaf(h4[i].w, w4.w, p);
            }
            p += __shfl_xor(p, 1);  p += __shfl_xor(p, 2);  p += __shfl_xor(p, 4);
            p += __shfl_xor(p, 8);  p += __shfl_xor(p, 16); p += __shfl_xor(p, 32);
            if (lane == k) res = p;
        }
        if (lane < 32) out[(size_t)t * 32 + lane] = res + bout[lane];
    }
}

// ======================================================================
extern "C" void kernel_launch(void* const* d_in, const int* in_sizes, int n_in,
                              void* d_out, int out_size, void* d_ws, size_t ws_size,
                              hipStream_t stream) {
    const int*   sent = (const int*)  d_in[0];
    const float* emb  = (const float*)d_in[1];
    const float* Wihf = (const float*)d_in[2];
    const float* Whhf = (const float*)d_in[3];
    const float* bihf = (const float*)d_in[4];
    const float* bhhf = (const float*)d_in[5];
    const float* Wihb = (const float*)d_in[6];
    const float* Whhb = (const float*)d_in[7];
    const float* bihb = (const float*)d_in[8];
    const float* bhhb = (const float*)d_in[9];
    const float* Wout = (const float*)d_in[10];
    const float* bout = (const float*)d_in[11];
    const float* h0   = (const float*)d_in[12];
    const float* c0   = (const float*)d_in[13];
    float* out = (float*)d_out;

    // workspace layout: pre (128 MB) | hcat (32 MB) | hbuf (16 KB)
    float* pre  = (float*)d_ws;
    float* hcat = pre + (size_t)2 * T_SEQ * G4;
    unsigned long long* hbuf = (unsigned long long*)(hcat + (size_t)T_SEQ * 1024);

    dim3 g1(G4 / 64, T_SEQ / 64, 2);
    k_pre<<<g1, 256, 0, stream>>>(sent, emb, Wihf, Wihb, bihf, bhhf, bihb, bhhb, pre);
    k_scan<<<32, 1024, 0, stream>>>(pre, Whhf, Whhb, h0, c0, hcat, hbuf);
    k_out<<<256, 256, 0, stream>>>(hcat, Wout, bout, out);
}